// Round 5
// baseline (149.482 us; speedup 1.0000x reference)
//
#include <hip/hip_runtime.h>
#include <hip/hip_bf16.h>

typedef __bf16 bf16x8 __attribute__((ext_vector_type(8)));
typedef __bf16 bf16x4 __attribute__((ext_vector_type(4)));
typedef float  f32x4  __attribute__((ext_vector_type(4)));

#define HF 128          // hidden dim
#define W1K 256         // W1 inner dim (2H)

// ============ Kernel 1: per-node linear precompute (v4, LDS W, high TLP) ===
// u[n] = A . x_src[n],  v[n] = B . x_dst[n]    (W1 = [A | B]; b1 added in k2)
// W1 (both halves) staged bf16 fragment-ordered in 64KB LDS once per block,
// amortized over ~25 subtiles. 512-thread blocks, ~110 VGPR -> 16 waves/CU.
// Per wave-task (16 nodes, one half): 8 prefetched f32x4 loads, 32
// ds_read_b128 + 32 MFMA, 8 packed stores. No barriers in steady state.
__global__ __launch_bounds__(512, 4) void node_precompute4(
    const float* __restrict__ x_src, const float* __restrict__ x_dst,
    const float* __restrict__ W1,
    __bf16* __restrict__ u, __bf16* __restrict__ v, int nNodes)
{
    __shared__ __align__(16) __bf16 wlds[64 * 64 * 8];   // 64 KiB

    const int tid  = threadIdx.x;
    const int lane = tid & 63;
    const int wid  = tid >> 6;      // 0..7
    const int l15  = lane & 15;
    const int lg   = lane >> 4;

    // ---- stage both W halves: fp32 global -> bf16 LDS, A-fragment order ----
    // frag f = h*32 + mt*4 + kk : W[h*128 + ...][row = mt*16+l15][k = kk*32+lg*8]
    for (int f = wid; f < 64; f += 8) {
        const int h  = f >> 5;
        const int mt = (f >> 2) & 7;
        const int kk = f & 3;
        const float* p = W1 + h * HF + (size_t)(mt * 16 + l15) * W1K
                       + kk * 32 + lg * 8;
        f32x4 a = *reinterpret_cast<const f32x4*>(p);
        f32x4 b = *reinterpret_cast<const f32x4*>(p + 4);
        bf16x8 w8;
        #pragma unroll
        for (int i = 0; i < 4; ++i) {
            w8[i]     = (__bf16)a[i];
            w8[i + 4] = (__bf16)b[i];
        }
        *reinterpret_cast<bf16x8*>(&wlds[(f * 64 + lane) * 8]) = w8;
    }
    __syncthreads();

    const int nst    = nNodes >> 4;          // 6250 subtiles per half (exact)
    const int T      = nst * 2;              // tasks: (subtile, half)
    const int stride = gridDim.x * 8;
    int task = blockIdx.x * 8 + wid;
    if (task >= T) return;

    // prefetch first task's x rows
    f32x4 nxt[8];
    {
        const int h = task & 1, st = task >> 1;
        const float* x = h ? x_dst : x_src;
        const float* rp = x + (size_t)(st * 16 + l15) * HF + lg * 8;
        #pragma unroll
        for (int kk = 0; kk < 4; ++kk) {
            nxt[2 * kk]     = *reinterpret_cast<const f32x4*>(rp + kk * 32);
            nxt[2 * kk + 1] = *reinterpret_cast<const f32x4*>(rp + kk * 32 + 4);
        }
    }

    while (task < T) {
        const int h  = task & 1, st = task >> 1;
        const int task2 = task + stride;

        // pack current x into bf16 B-fragments
        bf16x8 xb[4];
        #pragma unroll
        for (int kk = 0; kk < 4; ++kk) {
            bf16x8 t;
            #pragma unroll
            for (int i = 0; i < 4; ++i) {
                t[i]     = (__bf16)nxt[2 * kk][i];
                t[i + 4] = (__bf16)nxt[2 * kk + 1][i];
            }
            xb[kk] = t;
        }

        // prefetch next task (latency hides under MFMA + stores)
        if (task2 < T) {
            const int h2 = task2 & 1, st2 = task2 >> 1;
            const float* x2 = h2 ? x_dst : x_src;
            const float* rp = x2 + (size_t)(st2 * 16 + l15) * HF + lg * 8;
            #pragma unroll
            for (int kk = 0; kk < 4; ++kk) {
                nxt[2 * kk]     = *reinterpret_cast<const f32x4*>(rp + kk * 32);
                nxt[2 * kk + 1] = *reinterpret_cast<const f32x4*>(rp + kk * 32 + 4);
            }
        }

        f32x4 acc[8];
        #pragma unroll
        for (int mt = 0; mt < 8; ++mt) acc[mt] = (f32x4){0.f, 0.f, 0.f, 0.f};

        const __bf16* fb = &wlds[((size_t)h * 32 * 64 + lane) * 8];
        #pragma unroll
        for (int kk = 0; kk < 4; ++kk)
            #pragma unroll
            for (int mt = 0; mt < 8; ++mt) {
                bf16x8 wa = *reinterpret_cast<const bf16x8*>(
                    fb + (mt * 4 + kk) * 64 * 8);
                acc[mt] = __builtin_amdgcn_mfma_f32_16x16x32_bf16(
                    wa, xb[kk], acc[mt], 0, 0, 0);
            }

        // store: node = st*16 + l15 (exact, nNodes % 16 == 0 guarded by host)
        __bf16* op = (h ? v : u) + (size_t)(st * 16 + l15) * HF + lg * 4;
        #pragma unroll
        for (int mt = 0; mt < 8; ++mt) {
            bf16x4 o4;
            #pragma unroll
            for (int r = 0; r < 4; ++r) o4[r] = (__bf16)acc[mt][r];
            *reinterpret_cast<bf16x4*>(op + mt * 16) = o4;
        }
        task = task2;
    }
}

// ================= Kernel 2: per-edge score (pure gather) =================
// score[e] = W2 . relu(u[src[e]] + v[dst[e]] + b1) + b2
// 16 lanes per edge, 8 channels (16 B bf16) per lane, 4 edges per subgroup.
__global__ __launch_bounds__(256) void edge_score_kernel(
    const __bf16* __restrict__ u, const __bf16* __restrict__ v,
    const int* __restrict__ sidx, const int* __restrict__ didx,
    const float* __restrict__ W2, const float* __restrict__ b1,
    const float* __restrict__ b2,
    float* __restrict__ out, int nEdges)
{
    const int tid = threadIdx.x;
    const int sub = tid >> 4;        // 0..15
    const int l16 = tid & 15;

    const int ebase = blockIdx.x * 64 + sub;   // edges ebase + {0,16,32,48}

    float w2v[8], b1v[8];
    #pragma unroll
    for (int j = 0; j < 8; ++j) {
        w2v[j] = W2[l16 * 8 + j];
        b1v[j] = b1[l16 * 8 + j];
    }
    const float b2v = b2[0];

    int e[4], si[4], di[4];
    #pragma unroll
    for (int q = 0; q < 4; ++q) {
        e[q] = ebase + q * 16;
        const int c = min(e[q], nEdges - 1);
        si[q] = sidx[c];
        di[q] = didx[c];
    }

    bf16x8 uv[4], vv[4];
    #pragma unroll
    for (int q = 0; q < 4; ++q) {
        uv[q] = *reinterpret_cast<const bf16x8*>(u + (size_t)si[q] * HF + l16 * 8);
        vv[q] = *reinterpret_cast<const bf16x8*>(v + (size_t)di[q] * HF + l16 * 8);
    }

    float s[4] = {0.f, 0.f, 0.f, 0.f};
    #pragma unroll
    for (int q = 0; q < 4; ++q)
        #pragma unroll
        for (int j = 0; j < 8; ++j)
            s[q] += fmaxf((float)uv[q][j] + (float)vv[q][j] + b1v[j], 0.f) * w2v[j];

    #pragma unroll
    for (int off = 1; off < 16; off <<= 1)
        #pragma unroll
        for (int q = 0; q < 4; ++q)
            s[q] += __shfl_xor(s[q], off, 64);

    if (l16 == 0) {
        #pragma unroll
        for (int q = 0; q < 4; ++q)
            if (e[q] < nEdges) out[e[q]] = s[q] + b2v;
    }
}

// ================= Fallback: fused single kernel (round-1) =================
__global__ __launch_bounds__(256, 2) void edge_mlp_kernel(
    const float* __restrict__ x_src, const float* __restrict__ x_dst,
    const int*   __restrict__ src_idx, const int* __restrict__ dst_idx,
    const float* __restrict__ W1, const float* __restrict__ b1,
    const float* __restrict__ W2, const float* __restrict__ b2,
    float* __restrict__ out, int nEdges)
{
    __shared__ __align__(16) __bf16 w1lds[64 * 64 * 8];

    const int tid  = threadIdx.x;
    const int lane = tid & 63;
    const int wid  = tid >> 6;
    const int l15  = lane & 15;
    const int lg   = lane >> 4;

    for (int p = wid; p < 64; p += 4) {
        const int n   = p >> 3;
        const int kk  = p & 7;
        const float* src = W1 + (n * 16 + l15) * W1K + kk * 32 + lg * 8;
        bf16x8 w8;
        #pragma unroll
        for (int i = 0; i < 8; ++i) w8[i] = (__bf16)src[i];
        *reinterpret_cast<bf16x8*>(&w1lds[(p * 64 + lane) * 8]) = w8;
    }
    __syncthreads();

    float w2v[8], b1v[8];
    #pragma unroll
    for (int n = 0; n < 8; ++n) {
        w2v[n] = W2[n * 16 + l15];
        b1v[n] = b1[n * 16 + l15];
    }
    const float b2v = b2[0];

    const int ntiles = nEdges / 256;
    for (int t = blockIdx.x; t < ntiles; t += gridDim.x) {
        const int ebase = t * 256 + wid * 64;

        const float* srow[4];
        const float* drow[4];
        #pragma unroll
        for (int m = 0; m < 4; ++m) {
            const int e  = ebase + m * 16 + l15;
            srow[m] = x_src + (size_t)src_idx[e] * HF + lg * 8;
            drow[m] = x_dst + (size_t)dst_idx[e] * HF + lg * 8;
        }

        f32x4 acc[4][8];
        #pragma unroll
        for (int m = 0; m < 4; ++m)
            #pragma unroll
            for (int n = 0; n < 8; ++n)
                acc[m][n] = (f32x4){0.f, 0.f, 0.f, 0.f};

        #pragma unroll
        for (int kk = 0; kk < 8; ++kk) {
            bf16x8 a[4];
            #pragma unroll
            for (int m = 0; m < 4; ++m) {
                const float* p = (kk < 4) ? (srow[m] + kk * 32)
                                          : (drow[m] + (kk - 4) * 32);
                f32x4 u0 = *reinterpret_cast<const f32x4*>(p);
                f32x4 u1 = *reinterpret_cast<const f32x4*>(p + 4);
                bf16x8 av;
                #pragma unroll
                for (int i = 0; i < 4; ++i) {
                    av[i]     = (__bf16)u0[i];
                    av[i + 4] = (__bf16)u1[i];
                }
                a[m] = av;
            }
            #pragma unroll
            for (int n = 0; n < 8; ++n) {
                bf16x8 bfrag = *reinterpret_cast<const bf16x8*>(
                    &w1lds[((n * 8 + kk) * 64 + lane) * 8]);
                #pragma unroll
                for (int m = 0; m < 4; ++m) {
                    acc[m][n] = __builtin_amdgcn_mfma_f32_16x16x32_bf16(
                        a[m], bfrag, acc[m][n], 0, 0, 0);
                }
            }
        }

        #pragma unroll
        for (int m = 0; m < 4; ++m) {
            float part[4];
            #pragma unroll
            for (int r = 0; r < 4; ++r) {
                float s = 0.f;
                #pragma unroll
                for (int n = 0; n < 8; ++n) {
                    float hv = acc[m][n][r] + b1v[n];
                    s += fmaxf(hv, 0.f) * w2v[n];
                }
                part[r] = s;
            }
            #pragma unroll
            for (int off = 1; off < 16; off <<= 1) {
                #pragma unroll
                for (int r = 0; r < 4; ++r)
                    part[r] += __shfl_xor(part[r], off, 64);
            }
            if (l15 == m) {
                f32x4 v4 = { part[0] + b2v, part[1] + b2v,
                             part[2] + b2v, part[3] + b2v };
                *reinterpret_cast<f32x4*>(&out[ebase + m * 16 + lg * 4]) = v4;
            }
        }
    }
}

extern "C" void kernel_launch(void* const* d_in, const int* in_sizes, int n_in,
                              void* d_out, int out_size, void* d_ws, size_t ws_size,
                              hipStream_t stream) {
    const float* x_src  = (const float*)d_in[0];
    const float* x_dst  = (const float*)d_in[1];
    const int*   sidx   = (const int*)d_in[2];
    const int*   didx   = (const int*)d_in[3];
    const float* W1     = (const float*)d_in[4];
    const float* b1     = (const float*)d_in[5];
    const float* W2     = (const float*)d_in[6];
    const float* b2     = (const float*)d_in[7];
    float* out = (float*)d_out;

    const int nEdges = in_sizes[2];
    const int nNodes = in_sizes[0] / HF;

    const size_t needed = (size_t)2 * nNodes * HF * sizeof(__bf16);  // u + v
    if (ws_size >= needed && (nNodes & 15) == 0) {
        __bf16* u = (__bf16*)d_ws;
        __bf16* v = u + (size_t)nNodes * HF;

        node_precompute4<<<512, 512, 0, stream>>>(
            x_src, x_dst, W1, u, v, nNodes);

        const int egrid = (nEdges + 63) / 64;
        edge_score_kernel<<<egrid, 256, 0, stream>>>(
            u, v, sidx, didx, W2, b1, b2, out, nEdges);
    } else {
        edge_mlp_kernel<<<512, 256, 0, stream>>>(
            x_src, x_dst, sidx, didx, W1, b1, W2, b2, out, nEdges);
    }
}

// Round 6
// 87.209 us; speedup vs baseline: 1.7141x; 1.7141x over previous
//
#include <hip/hip_runtime.h>
#include <hip/hip_bf16.h>

typedef __bf16 bf16x8 __attribute__((ext_vector_type(8)));
typedef __bf16 bf16x4 __attribute__((ext_vector_type(4)));
typedef float  f32x4  __attribute__((ext_vector_type(4)));

#define HF 128          // hidden dim
#define W1K 256         // W1 inner dim (2H)

// ============ Kernel 1: per-node linear precompute (v5 = v4 + reg-budget fix)
// u[n] = A . x_src[n],  v[n] = B . x_dst[n]    (W1 = [A | B]; b1 added in k2)
// W1 (both halves) staged bf16 fragment-ordered in 64KB LDS once per block.
// __launch_bounds__(512, 2): 2 blocks/CU (CUDA semantics: arg2 = min BLOCKS
// per CU!) -> 128-VGPR cap -> no scratch spill (R5's (512,4) forced a 64-VGPR
// cap and spilled nxt[] to scratch: +85MB FETCH/WRITE, 120us).
__global__ __launch_bounds__(512, 2) void node_precompute5(
    const float* __restrict__ x_src, const float* __restrict__ x_dst,
    const float* __restrict__ W1,
    __bf16* __restrict__ u, __bf16* __restrict__ v, int nNodes)
{
    __shared__ __align__(16) __bf16 wlds[64 * 64 * 8];   // 64 KiB

    const int tid  = threadIdx.x;
    const int lane = tid & 63;
    const int wid  = tid >> 6;      // 0..7
    const int l15  = lane & 15;
    const int lg   = lane >> 4;

    // ---- stage both W halves: fp32 global -> bf16 LDS, A-fragment order ----
    // frag f = h*32 + mt*4 + kk : W[h*128+..][row = mt*16+l15][k = kk*32+lg*8]
    for (int f = wid; f < 64; f += 8) {
        const int h  = f >> 5;
        const int mt = (f >> 2) & 7;
        const int kk = f & 3;
        const float* p = W1 + h * HF + (size_t)(mt * 16 + l15) * W1K
                       + kk * 32 + lg * 8;
        f32x4 a = *reinterpret_cast<const f32x4*>(p);
        f32x4 b = *reinterpret_cast<const f32x4*>(p + 4);
        bf16x8 w8;
        #pragma unroll
        for (int i = 0; i < 4; ++i) {
            w8[i]     = (__bf16)a[i];
            w8[i + 4] = (__bf16)b[i];
        }
        *reinterpret_cast<bf16x8*>(&wlds[(f * 64 + lane) * 8]) = w8;
    }
    __syncthreads();

    const int nst    = nNodes >> 4;          // 6250 subtiles per half (exact)
    const int T      = nst * 2;              // tasks: (subtile, half)
    const int stride = gridDim.x * 8;
    int task = blockIdx.x * 8 + wid;
    if (task >= T) return;

    // prefetch first task's x rows
    f32x4 nxt[8];
    {
        const int h = task & 1, st = task >> 1;
        const float* x = h ? x_dst : x_src;
        const float* rp = x + (size_t)(st * 16 + l15) * HF + lg * 8;
        #pragma unroll
        for (int kk = 0; kk < 4; ++kk) {
            nxt[2 * kk]     = *reinterpret_cast<const f32x4*>(rp + kk * 32);
            nxt[2 * kk + 1] = *reinterpret_cast<const f32x4*>(rp + kk * 32 + 4);
        }
    }

    while (task < T) {
        const int h  = task & 1, st = task >> 1;
        const int task2 = task + stride;

        // pack current x into bf16 B-fragments
        bf16x8 xb[4];
        #pragma unroll
        for (int kk = 0; kk < 4; ++kk) {
            bf16x8 t;
            #pragma unroll
            for (int i = 0; i < 4; ++i) {
                t[i]     = (__bf16)nxt[2 * kk][i];
                t[i + 4] = (__bf16)nxt[2 * kk + 1][i];
            }
            xb[kk] = t;
        }

        // prefetch next task (latency hides under MFMA + stores)
        if (task2 < T) {
            const int h2 = task2 & 1, st2 = task2 >> 1;
            const float* x2 = h2 ? x_dst : x_src;
            const float* rp = x2 + (size_t)(st2 * 16 + l15) * HF + lg * 8;
            #pragma unroll
            for (int kk = 0; kk < 4; ++kk) {
                nxt[2 * kk]     = *reinterpret_cast<const f32x4*>(rp + kk * 32);
                nxt[2 * kk + 1] = *reinterpret_cast<const f32x4*>(rp + kk * 32 + 4);
            }
        }

        f32x4 acc[8];
        #pragma unroll
        for (int mt = 0; mt < 8; ++mt) acc[mt] = (f32x4){0.f, 0.f, 0.f, 0.f};

        const __bf16* fb = &wlds[((size_t)h * 32 * 64 + lane) * 8];
        #pragma unroll
        for (int kk = 0; kk < 4; ++kk)
            #pragma unroll
            for (int mt = 0; mt < 8; ++mt) {
                bf16x8 wa = *reinterpret_cast<const bf16x8*>(
                    fb + (mt * 4 + kk) * 64 * 8);
                acc[mt] = __builtin_amdgcn_mfma_f32_16x16x32_bf16(
                    wa, xb[kk], acc[mt], 0, 0, 0);
            }

        // store: node = st*16 + l15, channels mt*16 + lg*4 .. +4
        __bf16* op = (h ? v : u) + (size_t)(st * 16 + l15) * HF + lg * 4;
        #pragma unroll
        for (int mt = 0; mt < 8; ++mt) {
            bf16x4 o4;
            #pragma unroll
            for (int r = 0; r < 4; ++r) o4[r] = (__bf16)acc[mt][r];
            *reinterpret_cast<bf16x4*>(op + mt * 16) = o4;
        }
        task = task2;
    }
}

// ================= Kernel 2: per-edge score (pure gather) =================
// score[e] = W2 . relu(u[src[e]] + v[dst[e]] + b1) + b2
// 16 lanes per edge, 8 channels (16 B bf16) per lane, 4 edges per subgroup.
__global__ __launch_bounds__(256) void edge_score_kernel(
    const __bf16* __restrict__ u, const __bf16* __restrict__ v,
    const int* __restrict__ sidx, const int* __restrict__ didx,
    const float* __restrict__ W2, const float* __restrict__ b1,
    const float* __restrict__ b2,
    float* __restrict__ out, int nEdges)
{
    const int tid = threadIdx.x;
    const int sub = tid >> 4;        // 0..15
    const int l16 = tid & 15;

    const int ebase = blockIdx.x * 64 + sub;   // edges ebase + {0,16,32,48}

    float w2v[8], b1v[8];
    #pragma unroll
    for (int j = 0; j < 8; ++j) {
        w2v[j] = W2[l16 * 8 + j];
        b1v[j] = b1[l16 * 8 + j];
    }
    const float b2v = b2[0];

    int e[4], si[4], di[4];
    #pragma unroll
    for (int q = 0; q < 4; ++q) {
        e[q] = ebase + q * 16;
        const int c = min(e[q], nEdges - 1);
        si[q] = sidx[c];
        di[q] = didx[c];
    }

    bf16x8 uv[4], vv[4];
    #pragma unroll
    for (int q = 0; q < 4; ++q) {
        uv[q] = *reinterpret_cast<const bf16x8*>(u + (size_t)si[q] * HF + l16 * 8);
        vv[q] = *reinterpret_cast<const bf16x8*>(v + (size_t)di[q] * HF + l16 * 8);
    }

    float s[4] = {0.f, 0.f, 0.f, 0.f};
    #pragma unroll
    for (int q = 0; q < 4; ++q)
        #pragma unroll
        for (int j = 0; j < 8; ++j)
            s[q] += fmaxf((float)uv[q][j] + (float)vv[q][j] + b1v[j], 0.f) * w2v[j];

    #pragma unroll
    for (int off = 1; off < 16; off <<= 1)
        #pragma unroll
        for (int q = 0; q < 4; ++q)
            s[q] += __shfl_xor(s[q], off, 64);

    if (l16 == 0) {
        #pragma unroll
        for (int q = 0; q < 4; ++q)
            if (e[q] < nEdges) out[e[q]] = s[q] + b2v;
    }
}

// ================= Fallback: fused single kernel (round-1) =================
__global__ __launch_bounds__(256, 2) void edge_mlp_kernel(
    const float* __restrict__ x_src, const float* __restrict__ x_dst,
    const int*   __restrict__ src_idx, const int* __restrict__ dst_idx,
    const float* __restrict__ W1, const float* __restrict__ b1,
    const float* __restrict__ W2, const float* __restrict__ b2,
    float* __restrict__ out, int nEdges)
{
    __shared__ __align__(16) __bf16 w1lds[64 * 64 * 8];

    const int tid  = threadIdx.x;
    const int lane = tid & 63;
    const int wid  = tid >> 6;
    const int l15  = lane & 15;
    const int lg   = lane >> 4;

    for (int p = wid; p < 64; p += 4) {
        const int n   = p >> 3;
        const int kk  = p & 7;
        const float* src = W1 + (n * 16 + l15) * W1K + kk * 32 + lg * 8;
        bf16x8 w8;
        #pragma unroll
        for (int i = 0; i < 8; ++i) w8[i] = (__bf16)src[i];
        *reinterpret_cast<bf16x8*>(&w1lds[(p * 64 + lane) * 8]) = w8;
    }
    __syncthreads();

    float w2v[8], b1v[8];
    #pragma unroll
    for (int n = 0; n < 8; ++n) {
        w2v[n] = W2[n * 16 + l15];
        b1v[n] = b1[n * 16 + l15];
    }
    const float b2v = b2[0];

    const int ntiles = nEdges / 256;
    for (int t = blockIdx.x; t < ntiles; t += gridDim.x) {
        const int ebase = t * 256 + wid * 64;

        const float* srow[4];
        const float* drow[4];
        #pragma unroll
        for (int m = 0; m < 4; ++m) {
            const int e  = ebase + m * 16 + l15;
            srow[m] = x_src + (size_t)src_idx[e] * HF + lg * 8;
            drow[m] = x_dst + (size_t)dst_idx[e] * HF + lg * 8;
        }

        f32x4 acc[4][8];
        #pragma unroll
        for (int m = 0; m < 4; ++m)
            #pragma unroll
            for (int n = 0; n < 8; ++n)
                acc[m][n] = (f32x4){0.f, 0.f, 0.f, 0.f};

        #pragma unroll
        for (int kk = 0; kk < 8; ++kk) {
            bf16x8 a[4];
            #pragma unroll
            for (int m = 0; m < 4; ++m) {
                const float* p = (kk < 4) ? (srow[m] + kk * 32)
                                          : (drow[m] + (kk - 4) * 32);
                f32x4 u0 = *reinterpret_cast<const f32x4*>(p);
                f32x4 u1 = *reinterpret_cast<const f32x4*>(p + 4);
                bf16x8 av;
                #pragma unroll
                for (int i = 0; i < 4; ++i) {
                    av[i]     = (__bf16)u0[i];
                    av[i + 4] = (__bf16)u1[i];
                }
                a[m] = av;
            }
            #pragma unroll
            for (int n = 0; n < 8; ++n) {
                bf16x8 bfrag = *reinterpret_cast<const bf16x8*>(
                    &w1lds[((n * 8 + kk) * 64 + lane) * 8]);
                #pragma unroll
                for (int m = 0; m < 4; ++m) {
                    acc[m][n] = __builtin_amdgcn_mfma_f32_16x16x32_bf16(
                        a[m], bfrag, acc[m][n], 0, 0, 0);
                }
            }
        }

        #pragma unroll
        for (int m = 0; m < 4; ++m) {
            float part[4];
            #pragma unroll
            for (int r = 0; r < 4; ++r) {
                float s = 0.f;
                #pragma unroll
                for (int n = 0; n < 8; ++n) {
                    float hv = acc[m][n][r] + b1v[n];
                    s += fmaxf(hv, 0.f) * w2v[n];
                }
                part[r] = s;
            }
            #pragma unroll
            for (int off = 1; off < 16; off <<= 1) {
                #pragma unroll
                for (int r = 0; r < 4; ++r)
                    part[r] += __shfl_xor(part[r], off, 64);
            }
            if (l15 == m) {
                f32x4 v4 = { part[0] + b2v, part[1] + b2v,
                             part[2] + b2v, part[3] + b2v };
                *reinterpret_cast<f32x4*>(&out[ebase + m * 16 + lg * 4]) = v4;
            }
        }
    }
}

extern "C" void kernel_launch(void* const* d_in, const int* in_sizes, int n_in,
                              void* d_out, int out_size, void* d_ws, size_t ws_size,
                              hipStream_t stream) {
    const float* x_src  = (const float*)d_in[0];
    const float* x_dst  = (const float*)d_in[1];
    const int*   sidx   = (const int*)d_in[2];
    const int*   didx   = (const int*)d_in[3];
    const float* W1     = (const float*)d_in[4];
    const float* b1     = (const float*)d_in[5];
    const float* W2     = (const float*)d_in[6];
    const float* b2     = (const float*)d_in[7];
    float* out = (float*)d_out;

    const int nEdges = in_sizes[2];
    const int nNodes = in_sizes[0] / HF;

    const size_t needed = (size_t)2 * nNodes * HF * sizeof(__bf16);  // u + v
    if (ws_size >= needed && (nNodes & 15) == 0) {
        __bf16* u = (__bf16*)d_ws;
        __bf16* v = u + (size_t)nNodes * HF;

        node_precompute5<<<512, 512, 0, stream>>>(
            x_src, x_dst, W1, u, v, nNodes);

        const int egrid = (nEdges + 63) / 64;
        edge_score_kernel<<<egrid, 256, 0, stream>>>(
            u, v, sidx, didx, W2, b1, b2, out, nEdges);
    } else {
        edge_mlp_kernel<<<512, 256, 0, stream>>>(
            x_src, x_dst, sidx, didx, W1, b1, W2, b2, out, nEdges);
    }
}